// Round 7
// baseline (207.462 us; speedup 1.0000x reference)
//
#include <hip/hip_runtime.h>
#include <math.h>

// CRITICAL: ban FMA contraction file-wide. 1-ulp iou shifts flip near-tie
// argmaxes vs numpy's correctly-rounded ref (rounds 2-4, absmax 69).
#pragma clang fp contract(off)

// Shapes: B=64, N=100, A=8732.
// Out layout (f32 flat): [0,BA) labels | [BA,5BA) boxes | [5BA,6BA) mask
//
// ROUND 7: restore the session-best r2 configuration EXACTLY (128.56us:
// LDS-staged iou, 2240 blocks, wave-uniform loads, in-loop __any trigger,
// scatter fused into encode, no prior[] array) -- r3/r5/r6 proved every
// structural deviation regresses (busy-cycles constant ~44us-equiv, stall
// grows). Two safe micro-changes only:
//  (1) pad-wave early-exit AFTER staging sync: 192 all-invalid waves (2.2%
//      of tasks) ran the full 100-gt loop producing only duplicate column
//      submissions (clamped clones of anchor AA-1, idempotent under max).
//  (2) full chunk unroll + __launch_bounds__(256,8): r2 compiled to VGPR=16
//      (rolled loop, few outstanding ds_reads, latency exposed in the tail
//      round). Cap is 64 VGPR at 8 blocks/CU -- let the compiler batch.
//
// colmax u64[B*N]: init by prior (prior_bits<<32 | 0: low=0 loses ties to
// genuine submissions low>=1), atomicMax'd by iou, consumed by encode
// (fused, colmax in ws) or scatter (fallback, colmax in out's boxes region).

#define AA 8732
#define NN 100
#define BB 64
#define NTILE 35              // ceil(AA/256)
#define EPS_F 1e-6f
#define OVR_FLAG 0x10000
#define POS_BIT  0x8000
// qa = inter*v_rcp(uni): rel err <= ~1.8e-7. DEFL=1-5e-7 deflation makes all
// filters rigorous one-sided bounds (HW-validated rounds 8/10/11 + r2).
#define DEFL 0.9999995f

__constant__ int FM_SIZE[6] = {38, 19, 10, 5, 3, 1};
__constant__ int FM_NF[6]   = {4, 6, 6, 6, 4, 4};
__constant__ int FM_OFF[6]  = {0, 5776, 7942, 8542, 8692, 8728};

__device__ __forceinline__ void geom(const float4 axy, const float4 g,
                                     float area_a, float ag,
                                     float& inter, float& uni) {
    float ltx = fmaxf(axy.x, g.x);
    float lty = fmaxf(axy.y, g.y);
    float rbx = fminf(axy.z, g.z);
    float rby = fminf(axy.w, g.w);
    float w = fmaxf(rbx - ltx, 0.0f);
    float h = fmaxf(rby - lty, 0.0f);
    inter = w * h;
    uni = area_a + ag - inter;       // uni >= max area > 0 always
}

// ---------------------------------------------------------------------------
// Prior: per (b,n), rcp-approx max IoU over the <=30 center-cell anchors,
// deflated => SAFE lower bound of the column max. Initializes colmax with
// (prior_bits<<32 | 0): low=0 loses all ties to genuine submissions
// (low>=1), so the real winner always lands.
// ---------------------------------------------------------------------------
__global__ void prior_kernel(const float4* __restrict__ gt_boxes,
                             const float4* __restrict__ anchors_xyxy,
                             unsigned long long* __restrict__ colmax) {
    const int b = blockIdx.x;
    const int n = threadIdx.x;
    if (n >= NN) return;
    float4 g = gt_boxes[b * NN + n];
    float ag = (g.z - g.x) * (g.w - g.y);
    float cx = (g.x + g.z) * 0.5f;
    float cy = (g.y + g.w) * 0.5f;
    float best = 0.0f;
    for (int f = 0; f < 6; f++) {
        int s = FM_SIZE[f];
        int j = (int)(cx * (float)s); j = j < s - 1 ? j : s - 1;
        int i = (int)(cy * (float)s); i = i < s - 1 ? i : s - 1;
        int base = FM_OFF[f] + (i * s + j) * FM_NF[f];
        for (int k = 0; k < FM_NF[f]; k++) {
            float4 an = anchors_xyxy[base + k];
            float area_a = (an.z - an.x) * (an.w - an.y);
            float inter, uni;
            geom(an, g, area_a, ag, inter, uni);
            best = fmaxf(best, inter * __builtin_amdgcn_rcpf(uni));
        }
    }
    float defl = best * DEFL;        // <= colM*(1-3.2e-7): safe lower bound
    colmax[b * NN + n] = ((unsigned long long)__float_as_uint(defl)) << 32;
}

// ---------------------------------------------------------------------------
// Main-pass chunk [N0,N1): proven r2 body. Row: record mask vs pre-deflated
// running threshold rt (loop-carried chain is a single fmax; qa*DEFL is off
// the critical path); exact div deferred. Col: 1-cmp __any trigger vs LDS
// scurf (rare after prior priming); on trigger, exact div + packed u64
// butterfly ((bits<<32)|(AA-a): max iou then lowest a), lane 0 submits
// atomicMax + LDS scurf warm-up. Clamped clone lanes carry anchor AA-1's
// genuine packed value -- idempotent under max.
// Full unroll (<=32 iters): lets the compiler batch ds_reads (r2 compiled
// at VGPR=16 with a rolled loop; headroom is 64 at 8 blocks/CU).
// ---------------------------------------------------------------------------
template <int N0, int N1>
__device__ __forceinline__ void passChunk(
        const float4 axy, const float area_a, const unsigned lowkey,
        const int b, const int tid,
        const float4* __restrict__ sg,
        float2* sac,                                // x=area, y=scurf
        unsigned long long* __restrict__ colmax,
        float& rt, unsigned& rm)
{
    #pragma unroll
    for (int n = N0; n < N1; n++) {
        float4 g = sg[n];
        float2 aw = sac[n];        // one ds_read_b64 (stale .y = superset, safe)
        float inter, uni;
        geom(axy, g, area_a, aw.x, inter, uni);
        float qa = inter * __builtin_amdgcn_rcpf(uni);
        bool r = (qa > 0.0f) && (qa >= rt);          // row near-record
        rt = fmaxf(rt, qa * DEFL);
        rm |= (r ? 1u : 0u) << (n - N0);
        if (__any((int)(qa >= aw.y))) {              // column trigger (rare)
            float iou = inter / uni;                 // exact IEEE == numpy
            bool cc = (qa >= aw.y);
            unsigned long long p = cc
                ? ((((unsigned long long)__float_as_uint(iou)) << 32) |
                   (unsigned long long)lowkey) : 0ull;
            #pragma unroll
            for (int off = 32; off > 0; off >>= 1) {
                unsigned long long o = __shfl_xor(p, off);
                p = o > p ? o : p;
            }
            if ((tid & 63) == 0 && p != 0ull) {
                atomicMax(colmax + b * NN + n, p);
                atomicMax((unsigned*)&sac[n].y,
                    __float_as_uint(__uint_as_float((unsigned)(p >> 32)) * DEFL));
            }
        }
    }
}

__global__ __launch_bounds__(256, 8) void iou_pass_kernel(
        const float4* __restrict__ gt_boxes,        // B*N xyxy
        const float4* __restrict__ anchors_xyxy,    // A
        unsigned long long* __restrict__ colmax,    // B*N packed, prior-init
        int* __restrict__ out_slot)                 // -> out[5BA..6BA)
{
    const int b = blockIdx.y;
    const int tid = threadIdx.x;
    const int a = blockIdx.x * 256 + tid;
    const bool valid = (a < AA);
    const int ac = valid ? a : (AA - 1);

    __shared__ float4 sg[NN];
    __shared__ float2 sac[NN];     // x=area_g, y=scurf (deflated lower bound)

    if (tid < NN) {
        float4 g = gt_boxes[b * NN + tid];
        sg[tid] = g;
        // scurf seed == prior value (or a later colmax submission's raw iou
        // bits) re-deflated: rigorous lower bound either way.
        unsigned hi = (unsigned)(colmax[b * NN + tid] >> 32);
        sac[tid] = make_float2((g.z - g.x) * (g.w - g.y),
                               __uint_as_float(hi) * DEFL);
    }
    __syncthreads();

    // Pad-wave early-exit (AFTER staging sync: staging threads tid<100 may
    // live in a pad wave of the last block). A wave whose entire lane range
    // is >= AA contributes only duplicate clone submissions -- skip it.
    if (blockIdx.x * 256 + (tid & ~63) >= AA) return;

    const float4 axy = anchors_xyxy[ac];
    const float area_a = (axy.z - axy.x) * (axy.w - axy.y);
    const unsigned lowkey = (unsigned)(AA - ac);    // bigger = lower anchor

    // ---------------- Phase A ----------------
    float rt = 0.0f;               // running (deflated) row-record threshold
    unsigned rm0 = 0, rm1 = 0, rm2 = 0, rm3 = 0;
    passChunk<0, 32>(axy, area_a, lowkey, b, tid, sg, sac, colmax, rt, rm0);
    passChunk<32, 64>(axy, area_a, lowkey, b, tid, sg, sac, colmax, rt, rm1);
    passChunk<64, 96>(axy, area_a, lowkey, b, tid, sg, sac, colmax, rt, rm2);
    passChunk<96, NN>(axy, area_a, lowkey, b, tid, sg, sac, colmax, rt, rm3);

    // ---------------- Phase B: row replay (ascending n = numpy order) -----
    float bv = 0.0f;   // all-zero row: bv=0, bi=0 == numpy argmax
    int bi = 0;
    unsigned rms[4] = {rm0, rm1, rm2, rm3};
    #pragma unroll
    for (int h = 0; h < 4; h++) {
        unsigned m = rms[h];
        const int nb = h * 32;
        while (m) {
            int n = __builtin_ctz(m) + nb;
            m &= m - 1;
            float inter, uni;
            geom(axy, sg[n], area_a, sac[n].x, inter, uni);
            float qa = inter * __builtin_amdgcn_rcpf(uni);
            if (qa > 0.0f && qa >= rt) {             // final-threshold re-test
                float iou = inter / uni;             // exact IEEE == numpy
                if (iou > bv) { bv = iou; bi = n; }  // strict >: first max
            }
        }
    }

    if (valid) {
        // pos decision folded into the slot: exact bv vs 0.5 (override makes
        // pos true anyway; applied later via OVR table / OVR_FLAG).
        out_slot[(size_t)b * AA + a] = bi | (bv > 0.5f ? POS_BIT : 0);
    }
}

// ---------------------------------------------------------------------------
// FUSED encode: scatter folded in via LDS override table. Requires colmax
// outside out (ws). ovr[rel] = max n whose column winner is anchor abase+rel
// (atomicMax == np fancy-assignment last-n-wins). low==0 prior sentinel
// rejected by the low>=1 guard.
// ---------------------------------------------------------------------------
__global__ __launch_bounds__(256) void encode_fused_kernel(
        const int* __restrict__ gt_labels,
        const float4* __restrict__ gt_boxes,        // xyxy
        const float4* __restrict__ anchors_cxcywh,
        const unsigned long long* __restrict__ colmax,
        float* __restrict__ out)
{
    const int b = blockIdx.y;
    const int tid = threadIdx.x;
    const int abase = blockIdx.x * 256;

    __shared__ float4 sg[NN];
    __shared__ int    slab[NN];
    __shared__ int    ovr[256];

    ovr[tid] = -1;
    if (tid < NN) {
        sg[tid]   = gt_boxes[b * NN + tid];
        slab[tid] = gt_labels[b * NN + tid];
    }
    __syncthreads();
    if (tid < NN) {
        unsigned long long v = colmax[b * NN + tid];
        unsigned low = (unsigned)(v & 0xFFFFFFFFull);
        if (low >= 1u && low <= (unsigned)AA) {
            int rel = (AA - (int)low) - abase;       // column-winner anchor
            if (rel >= 0 && rel < 256) atomicMax(&ovr[rel], tid);
        }
    }
    __syncthreads();

    const int a = abase + tid;
    if (a >= AA) return;

    const size_t BA = (size_t)BB * AA;
    const size_t base = (size_t)b * AA + a;

    int s = ((const int*)(out + 5 * BA))[base];
    int o = ovr[tid];

    int idx; bool pos;
    if (o >= 0) { idx = o;          pos = true; }
    else        { idx = s & 0x7FFF; pos = (s & POS_BIT) != 0; }

    const float4 g = sg[idx];
    const float gcx = (g.x + g.z) * 0.5f;
    const float gcy = (g.y + g.w) * 0.5f;
    const float gw  = g.z - g.x;
    const float gh  = g.w - g.y;

    const float4 anc = anchors_cxcywh[a];
    const float ecx = (gcx - anc.x) / anc.z;
    const float ecy = (gcy - anc.y) / anc.w;
    const float ew  = logf((gw + EPS_F) / (anc.z + EPS_F));
    const float eh  = logf((gh + EPS_F) / (anc.w + EPS_F));

    out[base] = pos ? (float)slab[idx] : 0.0f;                   // labels
    ((float4*)(out + BA))[base] = make_float4(ecx, ecy, ew, eh); // boxes
    out[5 * BA + base] = pos ? 1.0f : 0.0f;                      // mask
}

// ---------------------------------------------------------------------------
// Fallback scatter + encode (HW-proven): used when ws_size < 51,200 B and
// colmax must alias out's boxes region (consumed before encode overwrites).
// ---------------------------------------------------------------------------
__global__ void scatter_kernel(const unsigned long long* __restrict__ colmax,
                               int* __restrict__ out_slot) {
    const int b = blockIdx.x;
    const int n = threadIdx.x;
    if (n < NN) {
        unsigned long long v = colmax[b * NN + n];
        unsigned low = (unsigned)(v & 0xFFFFFFFFull);
        if (low >= 1u && low <= (unsigned)AA) {
            int idx = AA - (int)low;
            atomicMax(&out_slot[(size_t)b * AA + idx], OVR_FLAG + n);
        }
    }
}

__global__ __launch_bounds__(256) void encode_kernel(
        const int* __restrict__ gt_labels,
        const float4* __restrict__ gt_boxes,        // xyxy
        const float4* __restrict__ anchors_cxcywh,
        float* __restrict__ out)
{
    const int b = blockIdx.y;
    const int tid = threadIdx.x;
    const int a = blockIdx.x * 256 + tid;

    __shared__ float4 sg[NN];
    __shared__ int    slab[NN];
    if (tid < NN) {
        sg[tid]   = gt_boxes[b * NN + tid];
        slab[tid] = gt_labels[b * NN + tid];
    }
    __syncthreads();
    if (a >= AA) return;

    const size_t BA = (size_t)BB * AA;
    const size_t base = (size_t)b * AA + a;

    int s = ((const int*)(out + 5 * BA))[base];

    int idx; bool pos;
    if (s >= OVR_FLAG) { idx = s - OVR_FLAG;  pos = true; }
    else               { idx = s & 0x7FFF;    pos = (s & POS_BIT) != 0; }

    const float4 g = sg[idx];
    const float gcx = (g.x + g.z) * 0.5f;
    const float gcy = (g.y + g.w) * 0.5f;
    const float gw  = g.z - g.x;
    const float gh  = g.w - g.y;

    const float4 anc = anchors_cxcywh[a];
    const float ecx = (gcx - anc.x) / anc.z;
    const float ecy = (gcy - anc.y) / anc.w;
    const float ew  = logf((gw + EPS_F) / (anc.z + EPS_F));
    const float eh  = logf((gh + EPS_F) / (anc.w + EPS_F));

    out[base] = pos ? (float)slab[idx] : 0.0f;                   // labels
    ((float4*)(out + BA))[base] = make_float4(ecx, ecy, ew, eh); // boxes
    out[5 * BA + base] = pos ? 1.0f : 0.0f;                      // mask
}

extern "C" void kernel_launch(void* const* d_in, const int* in_sizes, int n_in,
                              void* d_out, int out_size, void* d_ws, size_t ws_size,
                              hipStream_t stream) {
    const int*    gt_labels    = (const int*)d_in[0];
    const float4* gt_boxes     = (const float4*)d_in[1];
    const float4* anchors_cxcy = (const float4*)d_in[2];
    const float4* anchors_xyxy = (const float4*)d_in[3];
    float* out = (float*)d_out;

    const size_t BA = (size_t)BB * AA;
    int* slot = (int*)(out + 5 * BA);

    // Fused path needs colmax (B*N u64 = 51,200 B) to live outside out,
    // because encode overwrites the boxes region that hosts colmax in the
    // fallback. Engaged and proven in round 2 (ws >= 51,200).
    const bool fused = (ws_size >= (size_t)(BB * NN * 8));
    unsigned long long* colmax = fused
        ? (unsigned long long*)d_ws                  // 8B-aligned ws
        : (unsigned long long*)(out + BA);           // boxes region (proven)

    prior_kernel<<<BB, 128, 0, stream>>>(gt_boxes, anchors_xyxy, colmax);

    dim3 grid(NTILE, BB);    // (35, 64) — 1 anchor/thread, proven shape
    iou_pass_kernel<<<grid, 256, 0, stream>>>(gt_boxes, anchors_xyxy,
                                              colmax, slot);
    if (fused) {
        encode_fused_kernel<<<grid, 256, 0, stream>>>(gt_labels, gt_boxes,
                                                      anchors_cxcy, colmax,
                                                      out);
    } else {
        scatter_kernel<<<BB, 128, 0, stream>>>(colmax, slot);
        encode_kernel<<<grid, 256, 0, stream>>>(gt_labels, gt_boxes,
                                                anchors_cxcy, out);
    }
}

// Round 8
// 129.478 us; speedup vs baseline: 1.6023x; 1.6023x over previous
//
#include <hip/hip_runtime.h>
#include <math.h>

// CRITICAL: ban FMA contraction file-wide. 1-ulp iou shifts flip near-tie
// argmaxes vs numpy's correctly-rounded ref (rounds 2-4, absmax 69).
#pragma clang fp contract(off)

// Shapes: B=64, N=100, A=8732.
// Out layout (f32 flat): [0,BA) labels | [BA,5BA) boxes | [5BA,6BA) mask
//
// ROUND 8: restore the session-best round-2 configuration EXACTLY
// (128.56us total; iou 62.8us @ VALUBusy 75%, VGPR 16). Rounds 3-7 proved:
//  - r3/r5/r6 restructures: busy-cycles constant, stall/traffic grows.
//  - r7 full-unroll + launch_bounds(256,8): 64-VGPR cap + unrolled live
//    ranges -> scratch spill (161MB fetch / 200MB write) -> 146-220us.
//    NEVER pair aggressive unroll with a tightened VGPR cap.
// Only surviving delta vs r2: the pad-wave early-exit (r7-validated
// correct, zero-risk: skips 192 all-invalid waves after the staging sync).
//
// colmax u64[B*N]: init by prior (prior_bits<<32 | 0: low=0 loses ties to
// genuine submissions low>=1), atomicMax'd by iou, consumed by encode
// (fused, colmax in ws) or scatter (fallback, colmax in out's boxes region).

#define AA 8732
#define NN 100
#define BB 64
#define NTILE 35              // ceil(AA/256)
#define EPS_F 1e-6f
#define OVR_FLAG 0x10000
#define POS_BIT  0x8000
// qa = inter*v_rcp(uni): rel err <= ~1.8e-7. DEFL=1-5e-7 deflation makes all
// filters rigorous one-sided bounds (HW-validated rounds 8/10/11 + r2).
#define DEFL 0.9999995f

__constant__ int FM_SIZE[6] = {38, 19, 10, 5, 3, 1};
__constant__ int FM_NF[6]   = {4, 6, 6, 6, 4, 4};
__constant__ int FM_OFF[6]  = {0, 5776, 7942, 8542, 8692, 8728};

__device__ __forceinline__ void geom(const float4 axy, const float4 g,
                                     float area_a, float ag,
                                     float& inter, float& uni) {
    float ltx = fmaxf(axy.x, g.x);
    float lty = fmaxf(axy.y, g.y);
    float rbx = fminf(axy.z, g.z);
    float rby = fminf(axy.w, g.w);
    float w = fmaxf(rbx - ltx, 0.0f);
    float h = fmaxf(rby - lty, 0.0f);
    inter = w * h;
    uni = area_a + ag - inter;       // uni >= max area > 0 always
}

// ---------------------------------------------------------------------------
// Prior: per (b,n), rcp-approx max IoU over the <=30 center-cell anchors,
// deflated => SAFE lower bound of the column max. Initializes colmax with
// (prior_bits<<32 | 0): low=0 loses all ties to genuine submissions
// (low>=1), so the real winner always lands.
// ---------------------------------------------------------------------------
__global__ void prior_kernel(const float4* __restrict__ gt_boxes,
                             const float4* __restrict__ anchors_xyxy,
                             unsigned long long* __restrict__ colmax) {
    const int b = blockIdx.x;
    const int n = threadIdx.x;
    if (n >= NN) return;
    float4 g = gt_boxes[b * NN + n];
    float ag = (g.z - g.x) * (g.w - g.y);
    float cx = (g.x + g.z) * 0.5f;
    float cy = (g.y + g.w) * 0.5f;
    float best = 0.0f;
    for (int f = 0; f < 6; f++) {
        int s = FM_SIZE[f];
        int j = (int)(cx * (float)s); j = j < s - 1 ? j : s - 1;
        int i = (int)(cy * (float)s); i = i < s - 1 ? i : s - 1;
        int base = FM_OFF[f] + (i * s + j) * FM_NF[f];
        for (int k = 0; k < FM_NF[f]; k++) {
            float4 an = anchors_xyxy[base + k];
            float area_a = (an.z - an.x) * (an.w - an.y);
            float inter, uni;
            geom(an, g, area_a, ag, inter, uni);
            best = fmaxf(best, inter * __builtin_amdgcn_rcpf(uni));
        }
    }
    float defl = best * DEFL;        // <= colM*(1-3.2e-7): safe lower bound
    colmax[b * NN + n] = ((unsigned long long)__float_as_uint(defl)) << 32;
}

// ---------------------------------------------------------------------------
// Main-pass chunk [N0,N1): proven r2 body, rolled (#pragma unroll 4 --
// VGPR 16, no spill). Row: record mask vs pre-deflated running threshold rt
// (loop-carried chain is a single fmax; qa*DEFL off the critical path);
// exact div deferred. Col: 1-cmp __any trigger vs LDS scurf (rare after
// prior priming); on trigger, exact div + packed u64 butterfly
// ((bits<<32)|(AA-a): max iou then lowest a), lane 0 submits atomicMax +
// LDS scurf warm-up. Clamped clone lanes carry anchor AA-1's genuine packed
// value -- idempotent under max.
// ---------------------------------------------------------------------------
template <int N0, int N1>
__device__ __forceinline__ void passChunk(
        const float4 axy, const float area_a, const unsigned lowkey,
        const int b, const int tid,
        const float4* __restrict__ sg,
        float2* sac,                                // x=area, y=scurf
        unsigned long long* __restrict__ colmax,
        float& rt, unsigned& rm)
{
    #pragma unroll 4
    for (int n = N0; n < N1; n++) {
        float4 g = sg[n];
        float2 aw = sac[n];        // one ds_read_b64 (stale .y = superset, safe)
        float inter, uni;
        geom(axy, g, area_a, aw.x, inter, uni);
        float qa = inter * __builtin_amdgcn_rcpf(uni);
        bool r = (qa > 0.0f) && (qa >= rt);          // row near-record
        rt = fmaxf(rt, qa * DEFL);
        rm |= (r ? 1u : 0u) << (n - N0);
        if (__any((int)(qa >= aw.y))) {              // column trigger (rare)
            float iou = inter / uni;                 // exact IEEE == numpy
            bool cc = (qa >= aw.y);
            unsigned long long p = cc
                ? ((((unsigned long long)__float_as_uint(iou)) << 32) |
                   (unsigned long long)lowkey) : 0ull;
            #pragma unroll
            for (int off = 32; off > 0; off >>= 1) {
                unsigned long long o = __shfl_xor(p, off);
                p = o > p ? o : p;
            }
            if ((tid & 63) == 0 && p != 0ull) {
                atomicMax(colmax + b * NN + n, p);
                atomicMax((unsigned*)&sac[n].y,
                    __float_as_uint(__uint_as_float((unsigned)(p >> 32)) * DEFL));
            }
        }
    }
}

__global__ __launch_bounds__(256) void iou_pass_kernel(
        const float4* __restrict__ gt_boxes,        // B*N xyxy
        const float4* __restrict__ anchors_xyxy,    // A
        unsigned long long* __restrict__ colmax,    // B*N packed, prior-init
        int* __restrict__ out_slot)                 // -> out[5BA..6BA)
{
    const int b = blockIdx.y;
    const int tid = threadIdx.x;
    const int a = blockIdx.x * 256 + tid;
    const bool valid = (a < AA);
    const int ac = valid ? a : (AA - 1);

    __shared__ float4 sg[NN];
    __shared__ float2 sac[NN];     // x=area_g, y=scurf (deflated lower bound)

    if (tid < NN) {
        float4 g = gt_boxes[b * NN + tid];
        sg[tid] = g;
        // scurf seed == prior value (or a later colmax submission's raw iou
        // bits) re-deflated: rigorous lower bound either way.
        unsigned hi = (unsigned)(colmax[b * NN + tid] >> 32);
        sac[tid] = make_float2((g.z - g.x) * (g.w - g.y),
                               __uint_as_float(hi) * DEFL);
    }
    __syncthreads();

    // Pad-wave early-exit (AFTER staging sync; r7-validated correct). A wave
    // whose entire lane range is >= AA contributes only duplicate clone
    // submissions -- skip it.
    if (blockIdx.x * 256 + (tid & ~63) >= AA) return;

    const float4 axy = anchors_xyxy[ac];
    const float area_a = (axy.z - axy.x) * (axy.w - axy.y);
    const unsigned lowkey = (unsigned)(AA - ac);    // bigger = lower anchor

    // ---------------- Phase A ----------------
    float rt = 0.0f;               // running (deflated) row-record threshold
    unsigned rm0 = 0, rm1 = 0, rm2 = 0, rm3 = 0;
    passChunk<0, 32>(axy, area_a, lowkey, b, tid, sg, sac, colmax, rt, rm0);
    passChunk<32, 64>(axy, area_a, lowkey, b, tid, sg, sac, colmax, rt, rm1);
    passChunk<64, 96>(axy, area_a, lowkey, b, tid, sg, sac, colmax, rt, rm2);
    passChunk<96, NN>(axy, area_a, lowkey, b, tid, sg, sac, colmax, rt, rm3);

    // ---------------- Phase B: row replay (ascending n = numpy order) -----
    float bv = 0.0f;   // all-zero row: bv=0, bi=0 == numpy argmax
    int bi = 0;
    unsigned rms[4] = {rm0, rm1, rm2, rm3};
    #pragma unroll
    for (int h = 0; h < 4; h++) {
        unsigned m = rms[h];
        const int nb = h * 32;
        while (m) {
            int n = __builtin_ctz(m) + nb;
            m &= m - 1;
            float inter, uni;
            geom(axy, sg[n], area_a, sac[n].x, inter, uni);
            float qa = inter * __builtin_amdgcn_rcpf(uni);
            if (qa > 0.0f && qa >= rt) {             // final-threshold re-test
                float iou = inter / uni;             // exact IEEE == numpy
                if (iou > bv) { bv = iou; bi = n; }  // strict >: first max
            }
        }
    }

    if (valid) {
        // pos decision folded into the slot: exact bv vs 0.5 (override makes
        // pos true anyway; applied later via OVR table / OVR_FLAG).
        out_slot[(size_t)b * AA + a] = bi | (bv > 0.5f ? POS_BIT : 0);
    }
}

// ---------------------------------------------------------------------------
// FUSED encode: scatter folded in via LDS override table. Requires colmax
// outside out (ws). ovr[rel] = max n whose column winner is anchor abase+rel
// (atomicMax == np fancy-assignment last-n-wins). low==0 prior sentinel
// rejected by the low>=1 guard.
// ---------------------------------------------------------------------------
__global__ __launch_bounds__(256) void encode_fused_kernel(
        const int* __restrict__ gt_labels,
        const float4* __restrict__ gt_boxes,        // xyxy
        const float4* __restrict__ anchors_cxcywh,
        const unsigned long long* __restrict__ colmax,
        float* __restrict__ out)
{
    const int b = blockIdx.y;
    const int tid = threadIdx.x;
    const int abase = blockIdx.x * 256;

    __shared__ float4 sg[NN];
    __shared__ int    slab[NN];
    __shared__ int    ovr[256];

    ovr[tid] = -1;
    if (tid < NN) {
        sg[tid]   = gt_boxes[b * NN + tid];
        slab[tid] = gt_labels[b * NN + tid];
    }
    __syncthreads();
    if (tid < NN) {
        unsigned long long v = colmax[b * NN + tid];
        unsigned low = (unsigned)(v & 0xFFFFFFFFull);
        if (low >= 1u && low <= (unsigned)AA) {
            int rel = (AA - (int)low) - abase;       // column-winner anchor
            if (rel >= 0 && rel < 256) atomicMax(&ovr[rel], tid);
        }
    }
    __syncthreads();

    const int a = abase + tid;
    if (a >= AA) return;

    const size_t BA = (size_t)BB * AA;
    const size_t base = (size_t)b * AA + a;

    int s = ((const int*)(out + 5 * BA))[base];
    int o = ovr[tid];

    int idx; bool pos;
    if (o >= 0) { idx = o;          pos = true; }
    else        { idx = s & 0x7FFF; pos = (s & POS_BIT) != 0; }

    const float4 g = sg[idx];
    const float gcx = (g.x + g.z) * 0.5f;
    const float gcy = (g.y + g.w) * 0.5f;
    const float gw  = g.z - g.x;
    const float gh  = g.w - g.y;

    const float4 anc = anchors_cxcywh[a];
    const float ecx = (gcx - anc.x) / anc.z;
    const float ecy = (gcy - anc.y) / anc.w;
    const float ew  = logf((gw + EPS_F) / (anc.z + EPS_F));
    const float eh  = logf((gh + EPS_F) / (anc.w + EPS_F));

    out[base] = pos ? (float)slab[idx] : 0.0f;                   // labels
    ((float4*)(out + BA))[base] = make_float4(ecx, ecy, ew, eh); // boxes
    out[5 * BA + base] = pos ? 1.0f : 0.0f;                      // mask
}

// ---------------------------------------------------------------------------
// Fallback scatter + encode (HW-proven): used when ws_size < 51,200 B and
// colmax must alias out's boxes region (consumed before encode overwrites).
// ---------------------------------------------------------------------------
__global__ void scatter_kernel(const unsigned long long* __restrict__ colmax,
                               int* __restrict__ out_slot) {
    const int b = blockIdx.x;
    const int n = threadIdx.x;
    if (n < NN) {
        unsigned long long v = colmax[b * NN + n];
        unsigned low = (unsigned)(v & 0xFFFFFFFFull);
        if (low >= 1u && low <= (unsigned)AA) {
            int idx = AA - (int)low;
            atomicMax(&out_slot[(size_t)b * AA + idx], OVR_FLAG + n);
        }
    }
}

__global__ __launch_bounds__(256) void encode_kernel(
        const int* __restrict__ gt_labels,
        const float4* __restrict__ gt_boxes,        // xyxy
        const float4* __restrict__ anchors_cxcywh,
        float* __restrict__ out)
{
    const int b = blockIdx.y;
    const int tid = threadIdx.x;
    const int a = blockIdx.x * 256 + tid;

    __shared__ float4 sg[NN];
    __shared__ int    slab[NN];
    if (tid < NN) {
        sg[tid]   = gt_boxes[b * NN + tid];
        slab[tid] = gt_labels[b * NN + tid];
    }
    __syncthreads();
    if (a >= AA) return;

    const size_t BA = (size_t)BB * AA;
    const size_t base = (size_t)b * AA + a;

    int s = ((const int*)(out + 5 * BA))[base];

    int idx; bool pos;
    if (s >= OVR_FLAG) { idx = s - OVR_FLAG;  pos = true; }
    else               { idx = s & 0x7FFF;    pos = (s & POS_BIT) != 0; }

    const float4 g = sg[idx];
    const float gcx = (g.x + g.z) * 0.5f;
    const float gcy = (g.y + g.w) * 0.5f;
    const float gw  = g.z - g.x;
    const float gh  = g.w - g.y;

    const float4 anc = anchors_cxcywh[a];
    const float ecx = (gcx - anc.x) / anc.z;
    const float ecy = (gcy - anc.y) / anc.w;
    const float ew  = logf((gw + EPS_F) / (anc.z + EPS_F));
    const float eh  = logf((gh + EPS_F) / (anc.w + EPS_F));

    out[base] = pos ? (float)slab[idx] : 0.0f;                   // labels
    ((float4*)(out + BA))[base] = make_float4(ecx, ecy, ew, eh); // boxes
    out[5 * BA + base] = pos ? 1.0f : 0.0f;                      // mask
}

extern "C" void kernel_launch(void* const* d_in, const int* in_sizes, int n_in,
                              void* d_out, int out_size, void* d_ws, size_t ws_size,
                              hipStream_t stream) {
    const int*    gt_labels    = (const int*)d_in[0];
    const float4* gt_boxes     = (const float4*)d_in[1];
    const float4* anchors_cxcy = (const float4*)d_in[2];
    const float4* anchors_xyxy = (const float4*)d_in[3];
    float* out = (float*)d_out;

    const size_t BA = (size_t)BB * AA;
    int* slot = (int*)(out + 5 * BA);

    // Fused path needs colmax (B*N u64 = 51,200 B) to live outside out,
    // because encode overwrites the boxes region that hosts colmax in the
    // fallback. Engaged and proven in round 2 (ws >= 51,200).
    const bool fused = (ws_size >= (size_t)(BB * NN * 8));
    unsigned long long* colmax = fused
        ? (unsigned long long*)d_ws                  // 8B-aligned ws
        : (unsigned long long*)(out + BA);           // boxes region (proven)

    prior_kernel<<<BB, 128, 0, stream>>>(gt_boxes, anchors_xyxy, colmax);

    dim3 grid(NTILE, BB);    // (35, 64) — 1 anchor/thread, proven shape
    iou_pass_kernel<<<grid, 256, 0, stream>>>(gt_boxes, anchors_xyxy,
                                              colmax, slot);
    if (fused) {
        encode_fused_kernel<<<grid, 256, 0, stream>>>(gt_labels, gt_boxes,
                                                      anchors_cxcy, colmax,
                                                      out);
    } else {
        scatter_kernel<<<BB, 128, 0, stream>>>(colmax, slot);
        encode_kernel<<<grid, 256, 0, stream>>>(gt_labels, gt_boxes,
                                                anchors_cxcy, out);
    }
}